// Round 1
// baseline (352.474 us; speedup 1.0000x reference)
//
#include <hip/hip_runtime.h>

// Problem constants (fixed by setup_inputs: B=128, S=524288, target_len=256).
// L = S / target_len = 2048 floats per segment; segments tile flat memory.
#define SEG_LEN 2048
#define GAPS_INV (1.0f / 2047.0f)

// One wave (64 lanes) owns one whole segment of 2048 floats:
//   lane l, chunk c holds float4 at element (c*64 + l)*4, c = 0..7.
// Each of the 8 wave-wide loads covers a contiguous 1 KiB span (64 lanes x 16 B)
// -> perfect per-instruction coalescing, 8 VMEM per 8 KiB segment, no extra
// boundary load (neighbors fetched via shfl).
__global__ __launch_bounds__(256)
void seg_change_strength_kernel(const float* __restrict__ x,
                                float* __restrict__ out, int nseg) {
    const int lane   = threadIdx.x & 63;
    const int nwaves = (gridDim.x * 256) >> 6;            // total waves in grid
    const int wid    = blockIdx.x * 4 + (threadIdx.x >> 6);

    for (int seg = wid; seg < nseg; seg += nwaves) {
        const float4* p = (const float4*)(x + (long long)seg * SEG_LEN);

        float4 f[8];
        #pragma unroll
        for (int c = 0; c < 8; ++c)
            f[c] = p[c * 64 + lane];

        float s = 0.0f;
        #pragma unroll
        for (int c = 0; c < 8; ++c) {
            // 3 intra-float4 gaps
            s += fabsf(f[c].y - f[c].x)
               + fabsf(f[c].z - f[c].y)
               + fabsf(f[c].w - f[c].z);
            // gap between this float4's .w and the NEXT element:
            //   lanes 0..62: lane+1's chunk-c .x  (shfl_down by 1)
            //   lane 63    : lane 0's chunk-(c+1) .x (broadcast); for c==7 the
            //                segment ends at f[7].w -> substitute f[7].w (diff 0)
            float nx = __shfl_down(f[c].x, 1, 64);
            float nxt;
            if (c < 7) {
                float wrap = __shfl(f[c + 1].x, 0, 64);
                nxt = (lane == 63) ? wrap : nx;
            } else {
                nxt = (lane == 63) ? f[7].w : nx;
            }
            s += fabsf(nxt - f[c].w);
        }

        // Wave-64 butterfly reduction; lane 0 holds the segment sum.
        #pragma unroll
        for (int off = 32; off > 0; off >>= 1)
            s += __shfl_down(s, off, 64);

        if (lane == 0) out[seg] = s * GAPS_INV;
    }
}

extern "C" void kernel_launch(void* const* d_in, const int* in_sizes, int n_in,
                              void* d_out, int out_size, void* d_ws, size_t ws_size,
                              hipStream_t stream) {
    const float* x = (const float*)d_in[0];
    float* out = (float*)d_out;
    const int n = in_sizes[0];              // B * S = 67108864 floats
    const int nseg = n / SEG_LEN;           // 32768 segments

    // Persistent grid: 4096 blocks x 4 waves = 16384 waves, 2 segments each.
    // (Caps block count per Guideline 11; waves grid-stride the remainder.)
    int blocks = (nseg + 3) / 4;
    if (blocks > 4096) blocks = 4096;
    seg_change_strength_kernel<<<blocks, 256, 0, stream>>>(x, out, nseg);
}